// Round 8
// baseline (445.462 us; speedup 1.0000x reference)
//
#include <hip/hip_runtime.h>

typedef unsigned short u16;
typedef short bf16x8 __attribute__((ext_vector_type(8)));
typedef float f32x4 __attribute__((ext_vector_type(4)));

#define MFMA_BF16(a, b, c) __builtin_amdgcn_mfma_f32_16x16x32_bf16((a), (b), (c), 0, 0, 0)
#define ATT_SCALE 0.08838834764831845f  // 1/sqrt(128)

__device__ __forceinline__ u16 f2bf(float f) {
  union { float f; unsigned int u; } cv;
  cv.f = f;
  unsigned int u = cv.u + 0x7fffu + ((cv.u >> 16) & 1u);
  return (u16)(u >> 16);
}

// async global->LDS, 16B per lane; LDS dest wave-uniform base (HW adds lane*16)
__device__ __forceinline__ void gload_lds16(const u16* g, u16* l) {
  __builtin_amdgcn_global_load_lds(
      (const __attribute__((address_space(1))) unsigned int*)g,
      (__attribute__((address_space(3))) unsigned int*)l, 16, 0, 0);
}

// ---------------- prep: LN(x), AdaLN(latents), W transposes — one dispatch ----------------
__global__ __launch_bounds__(256) void prep_kernel(
    const float* __restrict__ x, const float* __restrict__ ln_w,
    const float* __restrict__ ln_b, const float* __restrict__ latents,
    const float* __restrict__ t_emb, const float* __restrict__ ssg,
    const float* __restrict__ Wq, const float* __restrict__ Wo,
    const float* __restrict__ Wkv,
    u16* __restrict__ xk_out, u16* __restrict__ lat_out,
    u16* __restrict__ WqT, u16* __restrict__ WoT, u16* __restrict__ WkvT)
{
  __shared__ float shmem[32 * 33];
  const int blk = blockIdx.x;
  const int tid = threadIdx.x;
  if (blk < 6144) {
    const bool is_x = blk < 4096;
    const int row = is_x ? blk : blk - 4096;
    const float* src = is_x ? (x + (size_t)row * 2048) : (latents + (size_t)row * 2048);
    const float4* xr = (const float4*)src;
    float4 v0 = xr[tid];
    float4 v1 = xr[tid + 256];
    float sum = v0.x + v0.y + v0.z + v0.w + v1.x + v1.y + v1.z + v1.w;
    float sq  = v0.x*v0.x + v0.y*v0.y + v0.z*v0.z + v0.w*v0.w
              + v1.x*v1.x + v1.y*v1.y + v1.z*v1.z + v1.w*v1.w;
    #pragma unroll
    for (int off = 32; off > 0; off >>= 1) {
      sum += __shfl_xor(sum, off);
      sq  += __shfl_xor(sq, off);
    }
    if ((tid & 63) == 0) { shmem[tid >> 6] = sum; shmem[(tid >> 6) + 4] = sq; }
    __syncthreads();
    sum = shmem[0] + shmem[1] + shmem[2] + shmem[3];
    sq  = shmem[4] + shmem[5] + shmem[6] + shmem[7];
    const float mean = sum * (1.0f / 2048.0f);
    const float var  = sq * (1.0f / 2048.0f) - mean * mean;
    const float rstd = rsqrtf(var + 1e-5f);
    if (is_x) {
      const float4* w4 = (const float4*)ln_w;
      const float4* b4 = (const float4*)ln_b;
      ushort4* orow = (ushort4*)(xk_out + (size_t)row * 2048);
      #pragma unroll
      for (int j = 0; j < 2; ++j) {
        const int idx = tid + j * 256;
        const float4 v = j ? v1 : v0;
        const float4 ww = w4[idx];
        const float4 bb = b4[idx];
        ushort4 o;
        o.x = f2bf((v.x - mean) * rstd * ww.x + bb.x);
        o.y = f2bf((v.y - mean) * rstd * ww.y + bb.y);
        o.z = f2bf((v.z - mean) * rstd * ww.z + bb.z);
        o.w = f2bf((v.w - mean) * rstd * ww.w + bb.w);
        orow[idx] = o;
      }
    } else {
      const int bidx = row >> 9;
      const float4* te = (const float4*)(t_emb + (size_t)bidx * 3 * 2048);
      const float4* sg = (const float4*)ssg;
      ushort4* orow = (ushort4*)(lat_out + (size_t)row * 2048);
      #pragma unroll
      for (int j = 0; j < 2; ++j) {
        const int idx = tid + j * 256;
        const float4 v = j ? v1 : v0;
        const float4 t0 = te[idx];        // shift row
        const float4 t1 = te[512 + idx];  // scale row
        const float4 s0 = sg[idx];
        const float4 s1 = sg[512 + idx];
        ushort4 o;
        o.x = f2bf(((v.x - mean) * rstd) * (1.0f + t1.x + s1.x) + (t0.x + s0.x));
        o.y = f2bf(((v.y - mean) * rstd) * (1.0f + t1.y + s1.y) + (t0.y + s0.y));
        o.z = f2bf(((v.z - mean) * rstd) * (1.0f + t1.z + s1.z) + (t0.z + s0.z));
        o.w = f2bf(((v.w - mean) * rstd) * (1.0f + t1.w + s1.w) + (t0.w + s0.w));
        orow[idx] = o;
      }
    }
  } else {
    int t = blk - 6144;
    const float* in;
    u16* outp;
    int C, cx, ry;
    if (t < 4096)      { in = Wq;  outp = WqT;  C = 2048; cx = t & 63;  ry = t >> 6; }
    else if (t < 8192) { t -= 4096; in = Wo;  outp = WoT;  C = 2048; cx = t & 63;  ry = t >> 6; }
    else               { t -= 8192; in = Wkv; outp = WkvT; C = 4096; cx = t & 127; ry = t >> 7; }
    float (*tile)[33] = (float(*)[33])shmem;
    const int R = 2048;
    const int c0 = cx * 32;
    const int r0 = ry * 32;
    const int tx = tid & 31;
    const int ty = tid >> 5;   // 0..7
    #pragma unroll
    for (int i = 0; i < 4; ++i)
      tile[ty + i * 8][tx] = in[(size_t)(r0 + ty + i * 8) * C + c0 + tx];
    __syncthreads();
    #pragma unroll
    for (int i = 0; i < 4; ++i)
      outp[(size_t)(c0 + ty + i * 8) * R + r0 + tx] = f2bf(tile[tx][ty + i * 8]);
  }
}

// ---------------- bf16 MFMA GEMM: BK=64, register staging pre-barrier (2-phase) ----------------
// used for q proj (mode 0) and out proj (mode 2); M=2048 shapes.
template<int BM>
__global__ __launch_bounds__(256) void gemm_bf16_kernel(
    const u16* __restrict__ A, const u16* __restrict__ BT,
    int Kd, int mode,
    const float* __restrict__ bias,
    u16* __restrict__ out_q, float* __restrict__ out_f,
    const float* __restrict__ t_emb, const float* __restrict__ ssg)
{
  constexpr int TI = BM / 32;        // wave covers BM/2 rows = TI 16-row tiles
  __shared__ u16 As[2][BM][40];      // padded: stride 40 elem = 80B
  __shared__ u16 Bs[2][128][40];
  const int tid  = threadIdx.x;
  const int lane = tid & 63;
  const int wv   = tid >> 6;
  const int wm   = wv & 1, wn = wv >> 1;
  const int quad = lane >> 4, lq = lane & 15;
  const int m0 = blockIdx.y * BM, n0 = blockIdx.x * 128;

  f32x4 acc[TI][4];
  #pragma unroll
  for (int i = 0; i < TI; ++i)
    #pragma unroll
    for (int j = 0; j < 4; ++j)
      acc[i][j] = (f32x4){0.f, 0.f, 0.f, 0.f};

  const int rB  = tid >> 1;
  const int hfB = (tid & 1) * 16;
  const u16* gB = BT + (size_t)(n0 + rB) * Kd + hfB;
  const int rA  = (BM == 128) ? (tid >> 1) : (tid >> 2);
  const int hA  = (BM == 128) ? 0 : ((tid >> 1) & 1);
  const int hfA = (tid & 1) * 16;
  const u16* gA = A + (size_t)(m0 + rA) * Kd + hA * 32 + hfA;

  for (int k0 = 0; k0 < Kd; k0 += 64) {
    uint4 a00, a01;
    a00 = *(const uint4*)(gA + k0);
    a01 = *(const uint4*)(gA + k0 + 8);
    const uint4 b00 = *(const uint4*)(gB + k0);
    const uint4 b01 = *(const uint4*)(gB + k0 + 8);
    const uint4 b10 = *(const uint4*)(gB + k0 + 32);
    const uint4 b11 = *(const uint4*)(gB + k0 + 40);
    __syncthreads();                 // prior iteration's LDS reads done
    *(uint4*)&As[hA][rA][hfA]     = a00;
    *(uint4*)&As[hA][rA][hfA + 8] = a01;
    *(uint4*)&Bs[0][rB][hfB]     = b00;
    *(uint4*)&Bs[0][rB][hfB + 8] = b01;
    *(uint4*)&Bs[1][rB][hfB]     = b10;
    *(uint4*)&Bs[1][rB][hfB + 8] = b11;
    __syncthreads();
    #pragma unroll
    for (int kk = 0; kk < 2; ++kk) {
      bf16x8 av[TI], bv[4];
      #pragma unroll
      for (int i = 0; i < TI; ++i)
        av[i] = *(const bf16x8*)&As[kk][wm * (BM / 2) + i * 16 + lq][quad * 8];
      #pragma unroll
      for (int j = 0; j < 4; ++j)
        bv[j] = *(const bf16x8*)&Bs[kk][wn * 64 + j * 16 + lq][quad * 8];
      #pragma unroll
      for (int i = 0; i < TI; ++i)
        #pragma unroll
        for (int j = 0; j < 4; ++j)
          acc[i][j] = MFMA_BF16(av[i], bv[j], acc[i][j]);
    }
  }

  // epilogue; C/D layout: col = lane&15, row = quad*4 + reg
  #pragma unroll
  for (int i = 0; i < TI; ++i) {
    const int mlb = m0 + wm * (BM / 2) + i * 16 + quad * 4;
    #pragma unroll
    for (int j = 0; j < 4; ++j) {
      const int n = n0 + wn * 64 + j * 16 + lq;
      const float bs = bias[n];
      if (mode == 0) {
        const int h = n >> 7, c = n & 127;
        #pragma unroll
        for (int rr = 0; rr < 4; ++rr) {
          const int m = mlb + rr;
          const int bb = m >> 9, l = m & 511;
          out_q[((size_t)(bb * 16 + h) * 512 + l) * 128 + c] =
              f2bf((acc[i][j][rr] + bs) * ATT_SCALE);
        }
      } else {
        #pragma unroll
        for (int rr = 0; rr < 4; ++rr) {
          const int m = mlb + rr;
          const int bb = m >> 9;
          const float g = t_emb[((size_t)bb * 3 + 2) * 2048 + n] + ssg[2 * 2048 + n];
          out_f[(size_t)m * 2048 + n] = (acc[i][j][rr] + bs) * g;
        }
      }
    }
  }
}

// ---------------- kv projection: 256x256 tile, 8-phase pipeline, counted vmcnt ----------------
// 512 thr = 8 waves (2M x 4N), BK=64, 128KB dbuf LDS, raw s_barrier, vmcnt(6) once/tile.
#define KV_BARRIER() asm volatile("s_barrier" ::: "memory")

#define KV_MMA(MH, NH, BV)                                                     \
  do {                                                                         \
    _Pragma("unroll")                                                          \
    for (int i = 0; i < 4; ++i) {                                              \
      _Pragma("unroll")                                                        \
      for (int j = 0; j < 2; ++j) {                                            \
        acc[(MH)*4 + i][(NH)*2 + j] =                                          \
            MFMA_BF16(av[i][0], BV[j][0], acc[(MH)*4 + i][(NH)*2 + j]);        \
        acc[(MH)*4 + i][(NH)*2 + j] =                                          \
            MFMA_BF16(av[i][1], BV[j][1], acc[(MH)*4 + i][(NH)*2 + j]);        \
      }                                                                        \
    }                                                                          \
  } while (0)

__global__ __launch_bounds__(512, 2) void gemm_kv_8phase(
    const u16* __restrict__ A, const u16* __restrict__ BT,
    const float* __restrict__ bias,
    u16* __restrict__ out_k, u16* __restrict__ out_vT,
    const int* __restrict__ k_lens)
{
  extern __shared__ __align__(16) u16 lds[];
  u16* const Alds = lds;            // [2buf][2mh][128 rows][64] = 32768 elems
  u16* const Blds = lds + 32768;    // [2buf][2nh][128 rows][64]

  const int tid  = threadIdx.x;
  const int lane = tid & 63;
  const int wv   = tid >> 6;        // 0..7
  const int wm   = wv >> 2;         // 0..1 (M half)
  const int wn   = wv & 3;          // 0..3 (N quarter)
  const int quad = lane >> 4, lq = lane & 15;
  const int m0 = blockIdx.y * 256, n0 = blockIdx.x * 256;

  f32x4 acc[8][4];
  #pragma unroll
  for (int a = 0; a < 8; ++a)
    #pragma unroll
    for (int b = 0; b < 4; ++b)
      acc[a][b] = (f32x4){0.f, 0.f, 0.f, 0.f};

  const int kl = k_lens[m0 >> 10];
  const bool active = (m0 & 1023) < kl;   // block-uniform

  if (active) {
    const int l3 = lane >> 3;                       // row-in-chunk 0..7
    const int sgcol = (((lane & 7) - l3) & 7) * 8;  // inverse-swizzled src granule
    auto stageA = [&](int buf, int mh, int k0) {
      #pragma unroll
      for (int p = 0; p < 2; ++p) {
        const u16* src = A + (size_t)(m0 + p * 128 + mh * 64 + wv * 8 + l3) * 2048 + k0 + sgcol;
        gload_lds16(src, &Alds[(buf * 2 + mh) * 8192 + (p * 8 + wv) * 512]);
      }
    };
    auto stageB = [&](int buf, int nh, int k0) {
      #pragma unroll
      for (int p = 0; p < 2; ++p) {
        const int c = p * 8 + wv;
        const u16* src = BT + (size_t)(n0 + (c >> 2) * 64 + nh * 32 + (c & 3) * 8 + l3) * 2048 + k0 + sgcol;
        gload_lds16(src, &Blds[(buf * 2 + nh) * 8192 + c * 512]);
      }
    };

    bf16x8 av[4][2], bv0[2][2], bv1[2][2];
    const int posk0 = (quad + (lq & 7)) & 7;        // swizzled granule pos, kk=0
    const int posk1 = (4 + quad + (lq & 7)) & 7;    // kk=1
    auto read_av = [&](int buf, int mh) {
      #pragma unroll
      for (int i = 0; i < 4; ++i) {
        const int base = (buf * 2 + mh) * 8192 + (wm * 64 + i * 16 + lq) * 64;
        av[i][0] = *(const bf16x8*)&Alds[base + posk0 * 8];
        av[i][1] = *(const bf16x8*)&Alds[base + posk1 * 8];
      }
    };
    auto read_bv = [&](int buf, int nh, bf16x8 (*bv)[2]) {
      #pragma unroll
      for (int j = 0; j < 2; ++j) {
        const int base = (buf * 2 + nh) * 8192 + (wn * 32 + j * 16 + lq) * 64;
        bv[j][0] = *(const bf16x8*)&Blds[base + posk0 * 8];
        bv[j][1] = *(const bf16x8*)&Blds[base + posk1 * 8];
      }
    };

    const int nt = 32;   // K=2048 / BK=64
    stageA(0, 0, 0); stageB(0, 0, 0); stageA(0, 1, 0); stageB(0, 1, 0);
    stageA(1, 0, 64); stageB(1, 0, 64); stageA(1, 1, 64);
    asm volatile("s_waitcnt vmcnt(6)" ::: "memory");
    KV_BARRIER();

    for (int t = 0; t < nt; ++t) {
      const int cur = t & 1, nxt = cur ^ 1;
      read_av(cur, 0);
      read_bv(cur, 0, bv0);
      if (t + 1 < nt) stageB(nxt, 1, (t + 1) * 64);
      KV_BARRIER();
      __builtin_amdgcn_s_setprio(1);
      KV_MMA(0, 0, bv0);
      __builtin_amdgcn_s_setprio(0);
      KV_BARRIER();
      read_bv(cur, 1, bv1);
      if (t + 2 < nt) stageA(cur, 0, (t + 2) * 64);
      KV_BARRIER();
      __builtin_amdgcn_s_setprio(1);
      KV_MMA(0, 1, bv1);
      __builtin_amdgcn_s_setprio(0);
      KV_BARRIER();
      read_av(cur, 1);
      if (t + 2 < nt) stageB(cur, 0, (t + 2) * 64);
      KV_BARRIER();
      __builtin_amdgcn_s_setprio(1);
      KV_MMA(1, 0, bv0);
      __builtin_amdgcn_s_setprio(0);
      KV_BARRIER();
      if (t + 2 < nt) stageA(cur, 1, (t + 2) * 64);
      KV_BARRIER();
      __builtin_amdgcn_s_setprio(1);
      KV_MMA(1, 1, bv1);
      __builtin_amdgcn_s_setprio(0);
      if (t < nt - 2) {
        asm volatile("s_waitcnt vmcnt(6)" ::: "memory");   // 3 halves in flight
      } else if (t == nt - 2) {
        asm volatile("s_waitcnt vmcnt(0)" ::: "memory");   // final tile fully landed
      }
      KV_BARRIER();
    }
  }

  // epilogue; C/D: col = lq (n), row = quad*4 + rr (m)
  #pragma unroll
  for (int a = 0; a < 8; ++a) {
    const int mlb = m0 + wm * 128 + (a >> 2) * 64 + (a & 3) * 16 + quad * 4;
    #pragma unroll
    for (int b = 0; b < 4; ++b) {
      const int n = n0 + wn * 64 + (b >> 1) * 32 + (b & 1) * 16 + lq;
      const float bs = bias[n];
      if (n < 2048) {
        const int h = n >> 7, c = n & 127;
        #pragma unroll
        for (int rr = 0; rr < 4; ++rr) {
          const int m = mlb + rr;
          const int bb = m >> 10, kk = m & 1023;
          out_k[((size_t)(bb * 16 + h) * 1024 + kk) * 128 + c] = f2bf(acc[a][b][rr] + bs);
        }
      } else {
        const int n2 = n - 2048;
        const int h = n2 >> 7, c = n2 & 127;
        const int bb = mlb >> 10, kk = mlb & 1023;   // 4 consecutive kk
        ushort4 o4;
        o4.x = f2bf(acc[a][b][0] + bs);
        o4.y = f2bf(acc[a][b][1] + bs);
        o4.z = f2bf(acc[a][b][2] + bs);
        o4.w = f2bf(acc[a][b][3] + bs);
        *(ushort4*)&out_vT[((size_t)(bb * 16 + h) * 128 + c) * 1024 + kk] = o4;
      }
    }
  }
}

// ---------------- flash attention: LDS double-buffered K/V, ONE barrier per tile ----------------
// r6-verified: block staging amortizes L2 requests 4x across waves; bh%8->XCD
// clustering keeps K/V L2-resident (FETCH 25MB). r7-verified: de-staging loses.
// New: K/V double-buffered in LDS. Per tile: issue loads(t+1) -> compute tile t
// from buf[cur] (vmcnt wait drifts to after ~1000cyc of compute) -> write regs
// to buf[cur^1] -> ONE __syncthreads. Races: reads(cur) vs writes(cur^1) are
// disjoint; the barrier orders this tile's reads against next tile's writes.
// 'more' is block-uniform (nkt depends only on b).
__global__ __launch_bounds__(256) void attn_kernel(
    const u16* __restrict__ qb, const u16* __restrict__ kb,
    const u16* __restrict__ vT, const int* __restrict__ k_lens,
    const int* __restrict__ q_lens, u16* __restrict__ ao)
{
  extern __shared__ u16 smem[];
  u16 (*Ks)[64][132] = (u16 (*)[64][132])smem;                          // [2][64][132]
  u16 (*Vs)[128][68] = (u16 (*)[128][68])(smem + 2 * 64 * 132);         // [2][128][68]
  u16 (*Ps)[68]      = (u16 (*)[68])(smem + 2 * 64 * 132 + 2 * 128 * 68); // [64][68]
  const int tid  = threadIdx.x;
  const int w    = tid >> 6;
  const int lane = tid & 63;
  const int quad = lane >> 4, lq = lane & 15;
  const int bh = blockIdx.x;           // x-fastest -> XCD = bh % 8
  const int b  = bh >> 4;
  const int l0 = blockIdx.y * 64;
  const int kl = k_lens[b];
  const int ql = q_lens[b];

  bf16x8 qf[4];
  {
    const u16* qp = qb + ((size_t)bh * 512 + l0 + w * 16 + lq) * 128 + quad * 8;
    #pragma unroll
    for (int ks = 0; ks < 4; ++ks)
      qf[ks] = *(const bf16x8*)(qp + ks * 32);
  }

  const int krow = tid >> 4;
  const int kcol = tid & 15;
  const u16* kg = kb + ((size_t)bh * 1024 + krow) * 128 + kcol * 8;
  const int vrow = tid >> 3;
  const int vcol = tid & 7;
  const u16* vg = vT + (size_t)bh * 128 * 1024 + (size_t)vrow * 1024 + vcol * 8;

  f32x4 o[8];
  #pragma unroll
  for (int j = 0; j < 8; ++j) o[j] = (f32x4){0.f, 0.f, 0.f, 0.f};
  float mrun[4], lrun[4];
  #pragma unroll
  for (int rr = 0; rr < 4; ++rr) { mrun[rr] = -__builtin_inff(); lrun[rr] = 0.f; }

  const int nkt = (kl + 63) >> 6;
  uint4 kd[4], vd[4];
  // prologue: tile 0 -> regs -> LDS buf0
  #pragma unroll
  for (int p = 0; p < 4; ++p)
    kd[p] = *(const uint4*)(kg + (size_t)(p * 16) * 128);
  #pragma unroll
  for (int p = 0; p < 4; ++p)
    vd[p] = *(const uint4*)(vg + (size_t)p * 32 * 1024);
  #pragma unroll
  for (int p = 0; p < 4; ++p)
    *(uint4*)&Ks[0][krow + p * 16][kcol * 8] = kd[p];
  #pragma unroll
  for (int p = 0; p < 4; ++p)
    *(uint4*)&Vs[0][vrow + p * 32][vcol * 8] = vd[p];
  __syncthreads();

  int cur = 0;
  for (int kt = 0; kt < nkt; ++kt) {
    const bool more = (kt + 1 < nkt);   // block-uniform
    // issue next tile's loads now; vmcnt wait lands after the compute below
    if (more) {
      const int kn = (kt + 1) * 64;
      #pragma unroll
      for (int p = 0; p < 4; ++p)
        kd[p] = *(const uint4*)(kg + (size_t)(kn + p * 16) * 128);
      #pragma unroll
      for (int p = 0; p < 4; ++p)
        vd[p] = *(const uint4*)(vg + (size_t)p * 32 * 1024 + kn);
    }

    const int k0 = kt * 64;
    f32x4 s[4];
    #pragma unroll
    for (int ct = 0; ct < 4; ++ct) {
      s[ct] = (f32x4){0.f, 0.f, 0.f, 0.f};
      #pragma unroll
      for (int ks = 0; ks < 4; ++ks) {
        const bf16x8 kf = *(const bf16x8*)&Ks[cur][ct * 16 + lq][ks * 32 + quad * 8];
        s[ct] = MFMA_BF16(qf[ks], kf, s[ct]);
      }
    }
    #pragma unroll
    for (int ct = 0; ct < 4; ++ct) {
      const bool valid = (k0 + ct * 16 + lq) < kl;
      #pragma unroll
      for (int rr = 0; rr < 4; ++rr)
        s[ct][rr] = valid ? s[ct][rr] : -__builtin_inff();
    }
    float mnew[4], alpha[4], rs[4];
    #pragma unroll
    for (int rr = 0; rr < 4; ++rr) {
      float tm = fmaxf(fmaxf(s[0][rr], s[1][rr]), fmaxf(s[2][rr], s[3][rr]));
      tm = fmaxf(tm, __shfl_xor(tm, 1));
      tm = fmaxf(tm, __shfl_xor(tm, 2));
      tm = fmaxf(tm, __shfl_xor(tm, 4));
      tm = fmaxf(tm, __shfl_xor(tm, 8));
      const float mn = fmaxf(mrun[rr], tm);
      alpha[rr] = __expf(mrun[rr] - mn);
      mrun[rr] = mn;
      mnew[rr] = mn;
      rs[rr] = 0.f;
    }
    #pragma unroll
    for (int ct = 0; ct < 4; ++ct)
      #pragma unroll
      for (int rr = 0; rr < 4; ++rr) {
        const float p = __expf(s[ct][rr] - mnew[rr]);
        s[ct][rr] = p;
        rs[rr] += p;
      }
    #pragma unroll
    for (int rr = 0; rr < 4; ++rr) {
      float t = rs[rr];
      t += __shfl_xor(t, 1);
      t += __shfl_xor(t, 2);
      t += __shfl_xor(t, 4);
      t += __shfl_xor(t, 8);
      lrun[rr] = lrun[rr] * alpha[rr] + t;
    }
    #pragma unroll
    for (int j = 0; j < 8; ++j)
      #pragma unroll
      for (int rr = 0; rr < 4; ++rr)
        o[j][rr] *= alpha[rr];

    // P relayout via wave-private band (within-wave LDS ordering via lgkmcnt)
    #pragma unroll
    for (int ct = 0; ct < 4; ++ct)
      #pragma unroll
      for (int rr = 0; rr < 4; ++rr)
        Ps[w * 16 + quad * 4 + rr][ct * 16 + lq] = f2bf(s[ct][rr]);

    bf16x8 pf[2];
    pf[0] = *(const bf16x8*)&Ps[w * 16 + lq][quad * 8];
    pf[1] = *(const bf16x8*)&Ps[w * 16 + lq][32 + quad * 8];

    #pragma unroll
    for (int j = 0; j < 8; ++j) {
      #pragma unroll
      for (int kk = 0; kk < 2; ++kk) {
        const bf16x8 vf = *(const bf16x8*)&Vs[cur][j * 16 + lq][kk * 32 + quad * 8];
        o[j] = MFMA_BF16(pf[kk], vf, o[j]);
      }
    }

    // publish next tile into the other buffer (vmcnt drained here, post-compute)
    if (more) {
      #pragma unroll
      for (int p = 0; p < 4; ++p)
        *(uint4*)&Ks[cur ^ 1][krow + p * 16][kcol * 8] = kd[p];
      #pragma unroll
      for (int p = 0; p < 4; ++p)
        *(uint4*)&Vs[cur ^ 1][vrow + p * 32][vcol * 8] = vd[p];
    }
    __syncthreads();
    cur ^= 1;
  }

  const int h = bh & 15;
  #pragma unroll
  for (int rr = 0; rr < 4; ++rr) {
    const int row = l0 + w * 16 + quad * 4 + rr;
    const float inv = (row < ql) ? (1.0f / lrun[rr]) : 0.0f;
    u16* op = ao + ((size_t)b * 512 + row) * 2048 + h * 128 + lq;
    #pragma unroll
    for (int j = 0; j < 8; ++j)
      op[j * 16] = f2bf(o[j][rr] * inv);
  }
}

extern "C" void kernel_launch(void* const* d_in, const int* in_sizes, int n_in,
                              void* d_out, int out_size, void* d_ws, size_t ws_size,
                              hipStream_t stream) {
  (void)in_sizes; (void)n_in; (void)out_size; (void)ws_size;
  const float* x       = (const float*)d_in[0];
  const float* latents = (const float*)d_in[1];
  const float* t_emb   = (const float*)d_in[2];
  const int*   q_lens  = (const int*)d_in[3];
  const int*   k_lens  = (const int*)d_in[4];
  const float* ln_w    = (const float*)d_in[5];
  const float* ln_b    = (const float*)d_in[6];
  const float* ssg     = (const float*)d_in[7];
  const float* Wq      = (const float*)d_in[8];
  const float* bq      = (const float*)d_in[9];
  const float* Wkv     = (const float*)d_in[10];
  const float* bkv     = (const float*)d_in[11];
  const float* Wo      = (const float*)d_in[12];
  const float* bo      = (const float*)d_in[13];
  float* out = (float*)d_out;

  u16* ws = (u16*)d_ws;
  const size_t MEG = (size_t)1 << 20;      // elements
  u16* WqT  = ws;                 //  4M elems: (2048 x 2048) bf16, N-major
  u16* WoT  = ws + 4  * MEG;      //  4M
  u16* WkvT = ws + 8  * MEG;      //  8M: (4096 x 2048)
  u16* xk   = ws + 16 * MEG;      //  8M: (B*K, 2048)
  u16* lat  = ws + 24 * MEG;      //  4M: (B*L, 2048)
  u16* qb   = ws + 28 * MEG;      //  4M: (B,H,L,C) pre-scaled
  u16* kbuf = ws + 32 * MEG;      //  8M: (B,H,K,C)
  u16* vTb  = ws + 40 * MEG;      //  8M: (B,H,C,K)
  u16* aob  = ws + 48 * MEG;      //  4M: (B*L, 2048)

  // dynamic LDS caps (idempotent)
  hipFuncSetAttribute(reinterpret_cast<const void*>(&gemm_kv_8phase),
                      hipFuncAttributeMaxDynamicSharedMemorySize, 131072);
  const int ATTN_LDS = (2 * 64 * 132 + 2 * 128 * 68 + 64 * 68) * 2;  // 77312 B
  hipFuncSetAttribute(reinterpret_cast<const void*>(&attn_kernel),
                      hipFuncAttributeMaxDynamicSharedMemorySize, ATTN_LDS);

  prep_kernel<<<dim3(22528), dim3(256), 0, stream>>>(
      x, ln_w, ln_b, latents, t_emb, ssg, Wq, Wo, Wkv,
      xk, lat, WqT, WoT, WkvT);

  // q = lat @ Wq + bq  (fused *1/sqrt(C))
  gemm_bf16_kernel<64><<<dim3(16, 32), dim3(256), 0, stream>>>(
      lat, WqT, 2048, 0, bq, qb, nullptr, nullptr, nullptr);
  // kv = xk @ Wkv + bkv  (8-phase 256² pipeline; masked m-tiles skip the K-loop)
  gemm_kv_8phase<<<dim3(16, 16), dim3(512), 131072, stream>>>(
      xk, WkvT, bkv, kbuf, vTb, k_lens);

  attn_kernel<<<dim3(64, 8), dim3(256), ATTN_LDS, stream>>>(
      qb, kbuf, vTb, k_lens, q_lens, aob);

  // out = (attn_out @ Wo + bo) * gate
  gemm_bf16_kernel<64><<<dim3(16, 32), dim3(256), 0, stream>>>(
      aob, WoT, 2048, 2, bo, nullptr, out, t_emb, ssg);
}

// Round 9
// 381.668 us; speedup vs baseline: 1.1671x; 1.1671x over previous
//
#include <hip/hip_runtime.h>

typedef unsigned short u16;
typedef short bf16x8 __attribute__((ext_vector_type(8)));
typedef float f32x4 __attribute__((ext_vector_type(4)));

#define MFMA_BF16(a, b, c) __builtin_amdgcn_mfma_f32_16x16x32_bf16((a), (b), (c), 0, 0, 0)
#define ATT_SCALE 0.08838834764831845f  // 1/sqrt(128)

__device__ __forceinline__ u16 f2bf(float f) {
  union { float f; unsigned int u; } cv;
  cv.f = f;
  unsigned int u = cv.u + 0x7fffu + ((cv.u >> 16) & 1u);
  return (u16)(u >> 16);
}

// async global->LDS, 16B per lane; LDS dest wave-uniform base (HW adds lane*16)
__device__ __forceinline__ void gload_lds16(const u16* g, u16* l) {
  __builtin_amdgcn_global_load_lds(
      (const __attribute__((address_space(1))) unsigned int*)g,
      (__attribute__((address_space(3))) unsigned int*)l, 16, 0, 0);
}

// ---------------- prep: LN(x), AdaLN(latents), W transposes — one dispatch ----------------
__global__ __launch_bounds__(256) void prep_kernel(
    const float* __restrict__ x, const float* __restrict__ ln_w,
    const float* __restrict__ ln_b, const float* __restrict__ latents,
    const float* __restrict__ t_emb, const float* __restrict__ ssg,
    const float* __restrict__ Wq, const float* __restrict__ Wo,
    const float* __restrict__ Wkv,
    u16* __restrict__ xk_out, u16* __restrict__ lat_out,
    u16* __restrict__ WqT, u16* __restrict__ WoT, u16* __restrict__ WkvT)
{
  __shared__ float shmem[32 * 33];
  const int blk = blockIdx.x;
  const int tid = threadIdx.x;
  if (blk < 6144) {
    const bool is_x = blk < 4096;
    const int row = is_x ? blk : blk - 4096;
    const float* src = is_x ? (x + (size_t)row * 2048) : (latents + (size_t)row * 2048);
    const float4* xr = (const float4*)src;
    float4 v0 = xr[tid];
    float4 v1 = xr[tid + 256];
    float sum = v0.x + v0.y + v0.z + v0.w + v1.x + v1.y + v1.z + v1.w;
    float sq  = v0.x*v0.x + v0.y*v0.y + v0.z*v0.z + v0.w*v0.w
              + v1.x*v1.x + v1.y*v1.y + v1.z*v1.z + v1.w*v1.w;
    #pragma unroll
    for (int off = 32; off > 0; off >>= 1) {
      sum += __shfl_xor(sum, off);
      sq  += __shfl_xor(sq, off);
    }
    if ((tid & 63) == 0) { shmem[tid >> 6] = sum; shmem[(tid >> 6) + 4] = sq; }
    __syncthreads();
    sum = shmem[0] + shmem[1] + shmem[2] + shmem[3];
    sq  = shmem[4] + shmem[5] + shmem[6] + shmem[7];
    const float mean = sum * (1.0f / 2048.0f);
    const float var  = sq * (1.0f / 2048.0f) - mean * mean;
    const float rstd = rsqrtf(var + 1e-5f);
    if (is_x) {
      const float4* w4 = (const float4*)ln_w;
      const float4* b4 = (const float4*)ln_b;
      ushort4* orow = (ushort4*)(xk_out + (size_t)row * 2048);
      #pragma unroll
      for (int j = 0; j < 2; ++j) {
        const int idx = tid + j * 256;
        const float4 v = j ? v1 : v0;
        const float4 ww = w4[idx];
        const float4 bb = b4[idx];
        ushort4 o;
        o.x = f2bf((v.x - mean) * rstd * ww.x + bb.x);
        o.y = f2bf((v.y - mean) * rstd * ww.y + bb.y);
        o.z = f2bf((v.z - mean) * rstd * ww.z + bb.z);
        o.w = f2bf((v.w - mean) * rstd * ww.w + bb.w);
        orow[idx] = o;
      }
    } else {
      const int bidx = row >> 9;
      const float4* te = (const float4*)(t_emb + (size_t)bidx * 3 * 2048);
      const float4* sg = (const float4*)ssg;
      ushort4* orow = (ushort4*)(lat_out + (size_t)row * 2048);
      #pragma unroll
      for (int j = 0; j < 2; ++j) {
        const int idx = tid + j * 256;
        const float4 v = j ? v1 : v0;
        const float4 t0 = te[idx];        // shift row
        const float4 t1 = te[512 + idx];  // scale row
        const float4 s0 = sg[idx];
        const float4 s1 = sg[512 + idx];
        ushort4 o;
        o.x = f2bf(((v.x - mean) * rstd) * (1.0f + t1.x + s1.x) + (t0.x + s0.x));
        o.y = f2bf(((v.y - mean) * rstd) * (1.0f + t1.y + s1.y) + (t0.y + s0.y));
        o.z = f2bf(((v.z - mean) * rstd) * (1.0f + t1.z + s1.z) + (t0.z + s0.z));
        o.w = f2bf(((v.w - mean) * rstd) * (1.0f + t1.w + s1.w) + (t0.w + s0.w));
        orow[idx] = o;
      }
    }
  } else {
    int t = blk - 6144;
    const float* in;
    u16* outp;
    int C, cx, ry;
    if (t < 4096)      { in = Wq;  outp = WqT;  C = 2048; cx = t & 63;  ry = t >> 6; }
    else if (t < 8192) { t -= 4096; in = Wo;  outp = WoT;  C = 2048; cx = t & 63;  ry = t >> 6; }
    else               { t -= 8192; in = Wkv; outp = WkvT; C = 4096; cx = t & 127; ry = t >> 7; }
    float (*tile)[33] = (float(*)[33])shmem;
    const int R = 2048;
    const int c0 = cx * 32;
    const int r0 = ry * 32;
    const int tx = tid & 31;
    const int ty = tid >> 5;   // 0..7
    #pragma unroll
    for (int i = 0; i < 4; ++i)
      tile[ty + i * 8][tx] = in[(size_t)(r0 + ty + i * 8) * C + c0 + tx];
    __syncthreads();
    #pragma unroll
    for (int i = 0; i < 4; ++i)
      outp[(size_t)(c0 + ty + i * 8) * R + r0 + tx] = f2bf(tile[tx][ty + i * 8]);
  }
}

// ---------------- bf16 MFMA GEMM: BK=64, register staging pre-barrier (2-phase) ----------------
// used for q proj (mode 0) and out proj (mode 2); M=2048 shapes.
template<int BM>
__global__ __launch_bounds__(256) void gemm_bf16_kernel(
    const u16* __restrict__ A, const u16* __restrict__ BT,
    int Kd, int mode,
    const float* __restrict__ bias,
    u16* __restrict__ out_q, float* __restrict__ out_f,
    const float* __restrict__ t_emb, const float* __restrict__ ssg)
{
  constexpr int TI = BM / 32;        // wave covers BM/2 rows = TI 16-row tiles
  __shared__ u16 As[2][BM][40];      // padded: stride 40 elem = 80B
  __shared__ u16 Bs[2][128][40];
  const int tid  = threadIdx.x;
  const int lane = tid & 63;
  const int wv   = tid >> 6;
  const int wm   = wv & 1, wn = wv >> 1;
  const int quad = lane >> 4, lq = lane & 15;
  const int m0 = blockIdx.y * BM, n0 = blockIdx.x * 128;

  f32x4 acc[TI][4];
  #pragma unroll
  for (int i = 0; i < TI; ++i)
    #pragma unroll
    for (int j = 0; j < 4; ++j)
      acc[i][j] = (f32x4){0.f, 0.f, 0.f, 0.f};

  const int rB  = tid >> 1;
  const int hfB = (tid & 1) * 16;
  const u16* gB = BT + (size_t)(n0 + rB) * Kd + hfB;
  const int rA  = (BM == 128) ? (tid >> 1) : (tid >> 2);
  const int hA  = (BM == 128) ? 0 : ((tid >> 1) & 1);
  const int hfA = (tid & 1) * 16;
  const u16* gA = A + (size_t)(m0 + rA) * Kd + hA * 32 + hfA;

  for (int k0 = 0; k0 < Kd; k0 += 64) {
    uint4 a00, a01;
    a00 = *(const uint4*)(gA + k0);
    a01 = *(const uint4*)(gA + k0 + 8);
    const uint4 b00 = *(const uint4*)(gB + k0);
    const uint4 b01 = *(const uint4*)(gB + k0 + 8);
    const uint4 b10 = *(const uint4*)(gB + k0 + 32);
    const uint4 b11 = *(const uint4*)(gB + k0 + 40);
    __syncthreads();                 // prior iteration's LDS reads done
    *(uint4*)&As[hA][rA][hfA]     = a00;
    *(uint4*)&As[hA][rA][hfA + 8] = a01;
    *(uint4*)&Bs[0][rB][hfB]     = b00;
    *(uint4*)&Bs[0][rB][hfB + 8] = b01;
    *(uint4*)&Bs[1][rB][hfB]     = b10;
    *(uint4*)&Bs[1][rB][hfB + 8] = b11;
    __syncthreads();
    #pragma unroll
    for (int kk = 0; kk < 2; ++kk) {
      bf16x8 av[TI], bv[4];
      #pragma unroll
      for (int i = 0; i < TI; ++i)
        av[i] = *(const bf16x8*)&As[kk][wm * (BM / 2) + i * 16 + lq][quad * 8];
      #pragma unroll
      for (int j = 0; j < 4; ++j)
        bv[j] = *(const bf16x8*)&Bs[kk][wn * 64 + j * 16 + lq][quad * 8];
      #pragma unroll
      for (int i = 0; i < TI; ++i)
        #pragma unroll
        for (int j = 0; j < 4; ++j)
          acc[i][j] = MFMA_BF16(av[i], bv[j], acc[i][j]);
    }
  }

  // epilogue; C/D layout: col = lane&15, row = quad*4 + reg
  #pragma unroll
  for (int i = 0; i < TI; ++i) {
    const int mlb = m0 + wm * (BM / 2) + i * 16 + quad * 4;
    #pragma unroll
    for (int j = 0; j < 4; ++j) {
      const int n = n0 + wn * 64 + j * 16 + lq;
      const float bs = bias[n];
      if (mode == 0) {
        const int h = n >> 7, c = n & 127;
        #pragma unroll
        for (int rr = 0; rr < 4; ++rr) {
          const int m = mlb + rr;
          const int bb = m >> 9, l = m & 511;
          out_q[((size_t)(bb * 16 + h) * 512 + l) * 128 + c] =
              f2bf((acc[i][j][rr] + bs) * ATT_SCALE);
        }
      } else {
        #pragma unroll
        for (int rr = 0; rr < 4; ++rr) {
          const int m = mlb + rr;
          const int bb = m >> 9;
          const float g = t_emb[((size_t)bb * 3 + 2) * 2048 + n] + ssg[2 * 2048 + n];
          out_f[(size_t)m * 2048 + n] = (acc[i][j][rr] + bs) * g;
        }
      }
    }
  }
}

// ---------------- kv projection: 256x256 tile, 8-phase pipeline, counted vmcnt ----------------
// 512 thr = 8 waves (2M x 4N), BK=64, 128KB dbuf LDS, raw s_barrier, vmcnt(6) once/tile.
#define KV_BARRIER() asm volatile("s_barrier" ::: "memory")

#define KV_MMA(MH, NH, BV)                                                     \
  do {                                                                         \
    _Pragma("unroll")                                                          \
    for (int i = 0; i < 4; ++i) {                                              \
      _Pragma("unroll")                                                        \
      for (int j = 0; j < 2; ++j) {                                            \
        acc[(MH)*4 + i][(NH)*2 + j] =                                          \
            MFMA_BF16(av[i][0], BV[j][0], acc[(MH)*4 + i][(NH)*2 + j]);        \
        acc[(MH)*4 + i][(NH)*2 + j] =                                          \
            MFMA_BF16(av[i][1], BV[j][1], acc[(MH)*4 + i][(NH)*2 + j]);        \
      }                                                                        \
    }                                                                          \
  } while (0)

__global__ __launch_bounds__(512, 2) void gemm_kv_8phase(
    const u16* __restrict__ A, const u16* __restrict__ BT,
    const float* __restrict__ bias,
    u16* __restrict__ out_k, u16* __restrict__ out_vT,
    const int* __restrict__ k_lens)
{
  extern __shared__ __align__(16) u16 lds[];
  u16* const Alds = lds;            // [2buf][2mh][128 rows][64] = 32768 elems
  u16* const Blds = lds + 32768;    // [2buf][2nh][128 rows][64]

  const int tid  = threadIdx.x;
  const int lane = tid & 63;
  const int wv   = tid >> 6;        // 0..7
  const int wm   = wv >> 2;         // 0..1 (M half)
  const int wn   = wv & 3;          // 0..3 (N quarter)
  const int quad = lane >> 4, lq = lane & 15;
  const int m0 = blockIdx.y * 256, n0 = blockIdx.x * 256;

  f32x4 acc[8][4];
  #pragma unroll
  for (int a = 0; a < 8; ++a)
    #pragma unroll
    for (int b = 0; b < 4; ++b)
      acc[a][b] = (f32x4){0.f, 0.f, 0.f, 0.f};

  const int kl = k_lens[m0 >> 10];
  const bool active = (m0 & 1023) < kl;   // block-uniform

  if (active) {
    const int l3 = lane >> 3;                       // row-in-chunk 0..7
    const int sgcol = (((lane & 7) - l3) & 7) * 8;  // inverse-swizzled src granule
    auto stageA = [&](int buf, int mh, int k0) {
      #pragma unroll
      for (int p = 0; p < 2; ++p) {
        const u16* src = A + (size_t)(m0 + p * 128 + mh * 64 + wv * 8 + l3) * 2048 + k0 + sgcol;
        gload_lds16(src, &Alds[(buf * 2 + mh) * 8192 + (p * 8 + wv) * 512]);
      }
    };
    auto stageB = [&](int buf, int nh, int k0) {
      #pragma unroll
      for (int p = 0; p < 2; ++p) {
        const int c = p * 8 + wv;
        const u16* src = BT + (size_t)(n0 + (c >> 2) * 64 + nh * 32 + (c & 3) * 8 + l3) * 2048 + k0 + sgcol;
        gload_lds16(src, &Blds[(buf * 2 + nh) * 8192 + c * 512]);
      }
    };

    bf16x8 av[4][2], bv0[2][2], bv1[2][2];
    const int posk0 = (quad + (lq & 7)) & 7;        // swizzled granule pos, kk=0
    const int posk1 = (4 + quad + (lq & 7)) & 7;    // kk=1
    auto read_av = [&](int buf, int mh) {
      #pragma unroll
      for (int i = 0; i < 4; ++i) {
        const int base = (buf * 2 + mh) * 8192 + (wm * 64 + i * 16 + lq) * 64;
        av[i][0] = *(const bf16x8*)&Alds[base + posk0 * 8];
        av[i][1] = *(const bf16x8*)&Alds[base + posk1 * 8];
      }
    };
    auto read_bv = [&](int buf, int nh, bf16x8 (*bv)[2]) {
      #pragma unroll
      for (int j = 0; j < 2; ++j) {
        const int base = (buf * 2 + nh) * 8192 + (wn * 32 + j * 16 + lq) * 64;
        bv[j][0] = *(const bf16x8*)&Blds[base + posk0 * 8];
        bv[j][1] = *(const bf16x8*)&Blds[base + posk1 * 8];
      }
    };

    const int nt = 32;   // K=2048 / BK=64
    stageA(0, 0, 0); stageB(0, 0, 0); stageA(0, 1, 0); stageB(0, 1, 0);
    stageA(1, 0, 64); stageB(1, 0, 64); stageA(1, 1, 64);
    asm volatile("s_waitcnt vmcnt(6)" ::: "memory");
    KV_BARRIER();

    for (int t = 0; t < nt; ++t) {
      const int cur = t & 1, nxt = cur ^ 1;
      read_av(cur, 0);
      read_bv(cur, 0, bv0);
      if (t + 1 < nt) stageB(nxt, 1, (t + 1) * 64);
      KV_BARRIER();
      __builtin_amdgcn_s_setprio(1);
      KV_MMA(0, 0, bv0);
      __builtin_amdgcn_s_setprio(0);
      KV_BARRIER();
      read_bv(cur, 1, bv1);
      if (t + 2 < nt) stageA(cur, 0, (t + 2) * 64);
      KV_BARRIER();
      __builtin_amdgcn_s_setprio(1);
      KV_MMA(0, 1, bv1);
      __builtin_amdgcn_s_setprio(0);
      KV_BARRIER();
      read_av(cur, 1);
      if (t + 2 < nt) stageB(cur, 0, (t + 2) * 64);
      KV_BARRIER();
      __builtin_amdgcn_s_setprio(1);
      KV_MMA(1, 0, bv0);
      __builtin_amdgcn_s_setprio(0);
      KV_BARRIER();
      if (t + 2 < nt) stageA(cur, 1, (t + 2) * 64);
      KV_BARRIER();
      __builtin_amdgcn_s_setprio(1);
      KV_MMA(1, 1, bv1);
      __builtin_amdgcn_s_setprio(0);
      if (t < nt - 2) {
        asm volatile("s_waitcnt vmcnt(6)" ::: "memory");   // 3 halves in flight
      } else if (t == nt - 2) {
        asm volatile("s_waitcnt vmcnt(0)" ::: "memory");   // final tile fully landed
      }
      KV_BARRIER();
    }
  }

  // epilogue; C/D: col = lq (n), row = quad*4 + rr (m)
  #pragma unroll
  for (int a = 0; a < 8; ++a) {
    const int mlb = m0 + wm * 128 + (a >> 2) * 64 + (a & 3) * 16 + quad * 4;
    #pragma unroll
    for (int b = 0; b < 4; ++b) {
      const int n = n0 + wn * 64 + (b >> 1) * 32 + (b & 1) * 16 + lq;
      const float bs = bias[n];
      if (n < 2048) {
        const int h = n >> 7, c = n & 127;
        #pragma unroll
        for (int rr = 0; rr < 4; ++rr) {
          const int m = mlb + rr;
          const int bb = m >> 10, kk = m & 1023;
          out_k[((size_t)(bb * 16 + h) * 1024 + kk) * 128 + c] = f2bf(acc[a][b][rr] + bs);
        }
      } else {
        const int n2 = n - 2048;
        const int h = n2 >> 7, c = n2 & 127;
        const int bb = mlb >> 10, kk = mlb & 1023;   // 4 consecutive kk
        ushort4 o4;
        o4.x = f2bf(acc[a][b][0] + bs);
        o4.y = f2bf(acc[a][b][1] + bs);
        o4.z = f2bf(acc[a][b][2] + bs);
        o4.w = f2bf(acc[a][b][3] + bs);
        *(ushort4*)&out_vT[((size_t)(bb * 16 + h) * 128 + c) * 1024 + kk] = o4;
      }
    }
  }
}

// ---------------- flash attention: r6 loop (verified 84.5us) + coalesced epilogue ----------------
// Loop: 2 barriers/tile, T14 prefetch after publish (r6-exact). bh%8->XCD clustering
// keeps K/V L2-resident. NEW: epilogue transposes O through an LDS band (aliased
// over Vs, dead after the post-loop barrier) and stores 16B/lane coalesced —
// r7-verified WRITE_SIZE 137MB -> 8MB (kills the partial-line write amplification).
__global__ __launch_bounds__(256) void attn_kernel(
    const u16* __restrict__ qb, const u16* __restrict__ kb,
    const u16* __restrict__ vT, const int* __restrict__ k_lens,
    const int* __restrict__ q_lens, u16* __restrict__ ao)
{
  __shared__ u16 Ks[64][132];   // keys x C; stride 264B -> 2-way banks (free)
  __shared__ __align__(16) u16 Vs[128][68];   // c x keys; stride 136B
  __shared__ u16 Ps[64][68];    // q x keys (wave-private 16-row bands)
  const int tid  = threadIdx.x;
  const int w    = tid >> 6;
  const int lane = tid & 63;
  const int quad = lane >> 4, lq = lane & 15;
  const int bh = blockIdx.x;           // x-fastest -> XCD = bh % 8
  const int b  = bh >> 4;
  const int l0 = blockIdx.y * 64;
  const int kl = k_lens[b];
  const int ql = q_lens[b];

  bf16x8 qf[4];
  {
    const u16* qp = qb + ((size_t)bh * 512 + l0 + w * 16 + lq) * 128 + quad * 8;
    #pragma unroll
    for (int ks = 0; ks < 4; ++ks)
      qf[ks] = *(const bf16x8*)(qp + ks * 32);
  }

  const int krow = tid >> 4;
  const int kcol = tid & 15;
  const u16* kg = kb + ((size_t)bh * 1024 + krow) * 128 + kcol * 8;
  const int vrow = tid >> 3;
  const int vcol = tid & 7;
  const u16* vg = vT + (size_t)bh * 128 * 1024 + (size_t)vrow * 1024 + vcol * 8;

  f32x4 o[8];
  #pragma unroll
  for (int j = 0; j < 8; ++j) o[j] = (f32x4){0.f, 0.f, 0.f, 0.f};
  float mrun[4], lrun[4];
  #pragma unroll
  for (int rr = 0; rr < 4; ++rr) { mrun[rr] = -__builtin_inff(); lrun[rr] = 0.f; }

  const int nkt = (kl + 63) >> 6;
  uint4 kd[4], vd[4];
  #pragma unroll
  for (int p = 0; p < 4; ++p)
    kd[p] = *(const uint4*)(kg + (size_t)(p * 16) * 128);
  #pragma unroll
  for (int p = 0; p < 4; ++p)
    vd[p] = *(const uint4*)(vg + (size_t)p * 32 * 1024);

  for (int kt = 0; kt < nkt; ++kt) {
    __syncthreads();                 // prior tile's LDS reads done
    #pragma unroll
    for (int p = 0; p < 4; ++p)
      *(uint4*)&Ks[krow + p * 16][kcol * 8] = kd[p];
    #pragma unroll
    for (int p = 0; p < 4; ++p)
      *(uint4*)&Vs[vrow + p * 32][vcol * 8] = vd[p];
    __syncthreads();

    // T14: issue next tile's global loads now; latency hides under compute below
    if (kt + 1 < nkt) {
      const int kn = (kt + 1) * 64;
      #pragma unroll
      for (int p = 0; p < 4; ++p)
        kd[p] = *(const uint4*)(kg + (size_t)(kn + p * 16) * 128);
      #pragma unroll
      for (int p = 0; p < 4; ++p)
        vd[p] = *(const uint4*)(vg + (size_t)p * 32 * 1024 + kn);
    }

    const int k0 = kt * 64;
    f32x4 s[4];
    #pragma unroll
    for (int ct = 0; ct < 4; ++ct) {
      s[ct] = (f32x4){0.f, 0.f, 0.f, 0.f};
      #pragma unroll
      for (int ks = 0; ks < 4; ++ks) {
        const bf16x8 kf = *(const bf16x8*)&Ks[ct * 16 + lq][ks * 32 + quad * 8];
        s[ct] = MFMA_BF16(qf[ks], kf, s[ct]);
      }
    }
    #pragma unroll
    for (int ct = 0; ct < 4; ++ct) {
      const bool valid = (k0 + ct * 16 + lq) < kl;
      #pragma unroll
      for (int rr = 0; rr < 4; ++rr)
        s[ct][rr] = valid ? s[ct][rr] : -__builtin_inff();
    }
    float mnew[4], alpha[4], rs[4];
    #pragma unroll
    for (int rr = 0; rr < 4; ++rr) {
      float tm = fmaxf(fmaxf(s[0][rr], s[1][rr]), fmaxf(s[2][rr], s[3][rr]));
      tm = fmaxf(tm, __shfl_xor(tm, 1));
      tm = fmaxf(tm, __shfl_xor(tm, 2));
      tm = fmaxf(tm, __shfl_xor(tm, 4));
      tm = fmaxf(tm, __shfl_xor(tm, 8));
      const float mn = fmaxf(mrun[rr], tm);
      alpha[rr] = __expf(mrun[rr] - mn);
      mrun[rr] = mn;
      mnew[rr] = mn;
      rs[rr] = 0.f;
    }
    #pragma unroll
    for (int ct = 0; ct < 4; ++ct)
      #pragma unroll
      for (int rr = 0; rr < 4; ++rr) {
        const float p = __expf(s[ct][rr] - mnew[rr]);
        s[ct][rr] = p;
        rs[rr] += p;
      }
    #pragma unroll
    for (int rr = 0; rr < 4; ++rr) {
      float t = rs[rr];
      t += __shfl_xor(t, 1);
      t += __shfl_xor(t, 2);
      t += __shfl_xor(t, 4);
      t += __shfl_xor(t, 8);
      lrun[rr] = lrun[rr] * alpha[rr] + t;
    }
    #pragma unroll
    for (int j = 0; j < 8; ++j)
      #pragma unroll
      for (int rr = 0; rr < 4; ++rr)
        o[j][rr] *= alpha[rr];

    #pragma unroll
    for (int ct = 0; ct < 4; ++ct)
      #pragma unroll
      for (int rr = 0; rr < 4; ++rr)
        Ps[w * 16 + quad * 4 + rr][ct * 16 + lq] = f2bf(s[ct][rr]);

    bf16x8 pf[2];
    pf[0] = *(const bf16x8*)&Ps[w * 16 + lq][quad * 8];
    pf[1] = *(const bf16x8*)&Ps[w * 16 + lq][32 + quad * 8];

    #pragma unroll
    for (int j = 0; j < 8; ++j) {
      #pragma unroll
      for (int kk = 0; kk < 2; ++kk) {
        const bf16x8 vf = *(const bf16x8*)&Vs[j * 16 + lq][kk * 32 + quad * 8];
        o[j] = MFMA_BF16(pf[kk], vf, o[j]);
      }
    }
  }

  // all waves done reading Vs -> safe to alias the O-transpose band over it
  __syncthreads();
  u16 (*Os)[136] = (u16 (*)[136])&Vs[0][0];   // 64 rows x 136 = 8704 u16 = sizeof(Vs)
  const int h = bh & 15;
  #pragma unroll
  for (int rr = 0; rr < 4; ++rr) {
    const int row = l0 + w * 16 + quad * 4 + rr;
    const float inv = (row < ql) ? (1.0f / lrun[rr]) : 0.0f;
    #pragma unroll
    for (int j = 0; j < 8; ++j)
      Os[w * 16 + quad * 4 + rr][j * 16 + lq] = f2bf(o[j][rr] * inv);
  }
  // wave-private band: within-wave LDS ordering via lgkmcnt; 16B/lane stores
  #pragma unroll
  for (int p = 0; p < 4; ++p) {
    const int lr = p * 4 + quad;             // local row 0..15
    ushort4 lo = *(const ushort4*)&Os[w * 16 + lr][lq * 8];
    ushort4 hi = *(const ushort4*)&Os[w * 16 + lr][lq * 8 + 4];
    u16* op = ao + ((size_t)b * 512 + l0 + w * 16 + lr) * 2048 + h * 128 + lq * 8;
    *(ushort4*)op = lo;
    *(ushort4*)(op + 4) = hi;
  }
}

extern "C" void kernel_launch(void* const* d_in, const int* in_sizes, int n_in,
                              void* d_out, int out_size, void* d_ws, size_t ws_size,
                              hipStream_t stream) {
  (void)in_sizes; (void)n_in; (void)out_size; (void)ws_size;
  const float* x       = (const float*)d_in[0];
  const float* latents = (const float*)d_in[1];
  const float* t_emb   = (const float*)d_in[2];
  const int*   q_lens  = (const int*)d_in[3];
  const int*   k_lens  = (const int*)d_in[4];
  const float* ln_w    = (const float*)d_in[5];
  const float* ln_b    = (const float*)d_in[6];
  const float* ssg     = (const float*)d_in[7];
  const float* Wq      = (const float*)d_in[8];
  const float* bq      = (const float*)d_in[9];
  const float* Wkv     = (const float*)d_in[10];
  const float* bkv     = (const float*)d_in[11];
  const float* Wo      = (const float*)d_in[12];
  const float* bo      = (const float*)d_in[13];
  float* out = (float*)d_out;

  u16* ws = (u16*)d_ws;
  const size_t MEG = (size_t)1 << 20;      // elements
  u16* WqT  = ws;                 //  4M elems: (2048 x 2048) bf16, N-major
  u16* WoT  = ws + 4  * MEG;      //  4M
  u16* WkvT = ws + 8  * MEG;      //  8M: (4096 x 2048)
  u16* xk   = ws + 16 * MEG;      //  8M: (B*K, 2048)
  u16* lat  = ws + 24 * MEG;      //  4M: (B*L, 2048)
  u16* qb   = ws + 28 * MEG;      //  4M: (B,H,L,C) pre-scaled
  u16* kbuf = ws + 32 * MEG;      //  8M: (B,H,K,C)
  u16* vTb  = ws + 40 * MEG;      //  8M: (B,H,C,K)
  u16* aob  = ws + 48 * MEG;      //  4M: (B*L, 2048)

  // allow 128KB dynamic LDS for the 8-phase kv kernel (idempotent)
  hipFuncSetAttribute(reinterpret_cast<const void*>(&gemm_kv_8phase),
                      hipFuncAttributeMaxDynamicSharedMemorySize, 131072);

  prep_kernel<<<dim3(22528), dim3(256), 0, stream>>>(
      x, ln_w, ln_b, latents, t_emb, ssg, Wq, Wo, Wkv,
      xk, lat, WqT, WoT, WkvT);

  // q = lat @ Wq + bq  (fused *1/sqrt(C))
  gemm_bf16_kernel<64><<<dim3(16, 32), dim3(256), 0, stream>>>(
      lat, WqT, 2048, 0, bq, qb, nullptr, nullptr, nullptr);
  // kv = xk @ Wkv + bkv  (8-phase 256² pipeline; masked m-tiles skip the K-loop)
  gemm_kv_8phase<<<dim3(16, 16), dim3(512), 131072, stream>>>(
      xk, WkvT, bkv, kbuf, vTb, k_lens);

  attn_kernel<<<dim3(64, 8), dim3(256), 0, stream>>>(qb, kbuf, vTb, k_lens, q_lens, aob);

  // out = (attn_out @ Wo + bo) * gate
  gemm_bf16_kernel<64><<<dim3(16, 32), dim3(256), 0, stream>>>(
      aob, WoT, 2048, 2, bo, nullptr, out, t_emb, ssg);
}